// Round 9
// baseline (575.656 us; speedup 1.0000x reference)
//
#include <hip/hip_runtime.h>

#define R_ 4096
#define S_ 64
#define H_ 256
#define N_ (R_ * S_)
#define FARD 1e10f

typedef __attribute__((ext_vector_type(4))) float f32x4;
typedef __attribute__((ext_vector_type(8))) short short8;

union U8 { short8 s; uint4 u; };

__device__ __forceinline__ unsigned int cvt_pk_bf16(float lo, float hi) {
    unsigned int r;
    asm("v_cvt_pk_bf16_f32 %0, %1, %2" : "=v"(r) : "v"(lo), "v"(hi));
    return r;
}
__device__ __forceinline__ unsigned short f2bf(float f) {
    unsigned int x = __float_as_uint(f);
    x += 0x7fffu + ((x >> 16) & 1u);          // RNE
    return (unsigned short)(x >> 16);
}
__device__ __forceinline__ float sigmoidf_(float x) { return 1.0f / (1.0f + expf(-x)); }

// Swizzled byte offset of bf16 act element (m, k); row = 512B. [T2]
__device__ __forceinline__ int act_byte(int m, int k) {
    return ((m << 9) + (k << 1)) ^ ((m & 7) << 4);
}
__device__ __forceinline__ short8 lds_read8(const unsigned short* base, int byte_off) {
    return *(const short8*)((const char*)base + byte_off);
}

// pack 4 fp32 acc -> relu -> 4 bf16 -> one 8B swizzled store
__device__ __forceinline__ void pack_store(unsigned short* act, int m, int n0, f32x4 a) {
    unsigned int u0 = cvt_pk_bf16(fmaxf(a[0], 0.f), fmaxf(a[1], 0.f));
    unsigned int u1 = cvt_pk_bf16(fmaxf(a[2], 0.f), fmaxf(a[3], 0.f));
    *(uint2*)((char*)act + act_byte(m, n0)) = make_uint2(u0, u1);
}

// ---- hidden layer, in-place. K-chunk outer loop: live = acc(64 AGPR)+B(16)+A(4)
// -> fits the 128-total cap needed for 4 waves/SIMD (R8 lesson: occupancy is
// register-file-bound at arch+acc totals; steps at 64/128/256).
__device__ void hidden_layer(unsigned short* act,
                             const short* __restrict__ Wt, const float* __restrict__ bias,
                             int lane, int wv)
{
    const int m0 = lane & 15;
    const int q  = lane >> 4;
    const int nw = wv << 6;

    f32x4 acc[4][4];
#pragma unroll
    for (int nt = 0; nt < 4; ++nt) {
        const float4 bv = *(const float4*)&bias[nw + nt * 16 + 4 * q];
#pragma unroll
        for (int mt = 0; mt < 4; ++mt) {
            acc[nt][mt][0] = bv.x; acc[nt][mt][1] = bv.y;
            acc[nt][mt][2] = bv.z; acc[nt][mt][3] = bv.w;
        }
    }

    const short* Abase = Wt + (nw + m0) * H_ + 8 * q;
#pragma unroll
    for (int kc = 0; kc < 8; ++kc) {               // K = 8 chunks of 32
        const int kb = kc * 32;
        short8 B[4];
#pragma unroll
        for (int mt = 0; mt < 4; ++mt)
            B[mt] = lds_read8(act, act_byte(mt * 16 + m0, kb + 8 * q));
#pragma unroll
        for (int nt = 0; nt < 4; ++nt) {
            short8 A = *(const short8*)(Abase + nt * 16 * H_ + kb);
#pragma unroll
            for (int mt = 0; mt < 4; ++mt)
                acc[nt][mt] = __builtin_amdgcn_mfma_f32_16x16x32_bf16(
                    A, B[mt], acc[nt][mt], 0, 0, 0);
        }
    }
    __syncthreads();   // all waves done READING act
#pragma unroll
    for (int nt = 0; nt < 4; ++nt)
#pragma unroll
        for (int mt = 0; mt < 4; ++mt)
            pack_store(act, mt * 16 + m0, nw + nt * 16 + 4 * q, acc[nt][mt]);
    __syncthreads();   // writes visible
}

// ---- input layer via MFMA (K padded to 32; only k=0..7 nonzero, held by q==0 lanes)
__device__ void input_mfma(const float* __restrict__ pts, const float* __restrict__ drs,
                           const float* __restrict__ tv,
                           const short* __restrict__ WinT, const float* __restrict__ bin,
                           unsigned short* act, int base, int lane, int wv)
{
    const int m0 = lane & 15;
    const int q  = lane >> 4;
    const int nw = wv << 6;

    short8 B[4];
#pragma unroll
    for (int mt = 0; mt < 4; ++mt) {
        U8 ub;
        if (q == 0) {
            const int s = base + mt * 16 + m0;
            float p0 = pts[s * 3 + 0], p1 = pts[s * 3 + 1], p2 = pts[s * 3 + 2];
            float e0 = drs[s * 3 + 0], e1 = drs[s * 3 + 1], e2 = drs[s * 3 + 2];
            float t  = tv[s];
            ub.u = make_uint4(cvt_pk_bf16(p0, p1), cvt_pk_bf16(p2, e0),
                              cvt_pk_bf16(e1, e2), cvt_pk_bf16(t, 0.f));
        } else {
            ub.u = make_uint4(0, 0, 0, 0);
        }
        B[mt] = ub.s;
    }

    f32x4 acc[4][4];
#pragma unroll
    for (int nt = 0; nt < 4; ++nt) {
        const float4 bv = *(const float4*)&bin[nw + nt * 16 + 4 * q];
#pragma unroll
        for (int mt = 0; mt < 4; ++mt) {
            acc[nt][mt][0] = bv.x; acc[nt][mt][1] = bv.y;
            acc[nt][mt][2] = bv.z; acc[nt][mt][3] = bv.w;
        }
    }
#pragma unroll
    for (int nt = 0; nt < 4; ++nt) {
        // rows k>=INK of WinT are zero, so q!=0 slices contribute 0
        short8 A = *(const short8*)&WinT[(nw + nt * 16 + m0) * 32 + 8 * q];
#pragma unroll
        for (int mt = 0; mt < 4; ++mt)
            acc[nt][mt] = __builtin_amdgcn_mfma_f32_16x16x32_bf16(A, B[mt], acc[nt][mt], 0, 0, 0);
    }
#pragma unroll
    for (int nt = 0; nt < 4; ++nt)
#pragma unroll
        for (int mt = 0; mt < 4; ++mt)
            pack_store(act, mt * 16 + m0, nw + nt * 16 + 4 * q, acc[nt][mt]);
    __syncthreads();
}

// ---- output layer via MFMA: wave wv owns samples [16wv,16wv+16); A = WoutT[16pad][256]
template <int OUTD>
__device__ void out_mfma(const unsigned short* act, const short* __restrict__ WoT,
                         const float* __restrict__ bout, float* obuf, int lane, int wv)
{
    const int m0 = lane & 15;
    const int q  = lane >> 4;
    const int m  = (wv << 4) + m0;

    f32x4 acc = {0.f, 0.f, 0.f, 0.f};
#pragma unroll
    for (int ks = 0; ks < 8; ++ks) {
        short8 A  = *(const short8*)&WoT[m0 * H_ + ks * 32 + 8 * q];
        short8 Bv = lds_read8(act, act_byte(m, ks * 32 + 8 * q));
        acc = __builtin_amdgcn_mfma_f32_16x16x32_bf16(A, Bv, acc, 0, 0, 0);
    }
    if (q == 0) {
        float4 v = make_float4(acc[0] + bout[0], acc[1] + bout[1],
                               acc[2] + bout[2], acc[3] + bout[3]);
        *(float4*)&obuf[m * 8] = v;
    }
    if (OUTD == 5 && q == 1) obuf[m * 8 + 4] = acc[0] + bout[4];
}

// 256 threads, 4 waves; __launch_bounds__(256,4) caps total regs at 128
// (64 AGPR acc + <=64 arch) -> 4 waves/SIMD.
__global__ __launch_bounds__(256, 4) void nerf_kernel(
    const float* __restrict__ points, const float* __restrict__ dirs,
    const float* __restrict__ z_vals, const float* __restrict__ timev,
    const float* __restrict__ sbin, const float* __restrict__ sbh, const float* __restrict__ sbout,
    const float* __restrict__ dbin, const float* __restrict__ dbh, const float* __restrict__ dbout,
    const short* __restrict__ wsb,
    float* __restrict__ out)
{
    __shared__ unsigned short act[64 * H_];     // 32KB, in-place
    __shared__ float souts[64 * 8];             // 2KB
    __shared__ float douts[64 * 8];             // 2KB

    const int tid  = threadIdx.x;
    const int lane = tid & 63;
    const int wv   = tid >> 6;
    const int ray  = blockIdx.x;
    const int base = ray * 64;

    const short* sWt   = wsb;
    const short* dWt   = wsb + 196608;
    const short* sWinT = wsb + 393216;
    const short* dWinT = wsb + 401408;
    const short* sWoT  = wsb + 409600;
    const short* dWoT  = wsb + 413696;

    // ---- static MLP ----
    input_mfma(points, dirs, timev, sWinT, sbin, act, base, lane, wv);
    hidden_layer(act, sWt + 0 * 65536, sbh + 0 * H_, lane, wv);
    hidden_layer(act, sWt + 1 * 65536, sbh + 1 * H_, lane, wv);
    hidden_layer(act, sWt + 2 * 65536, sbh + 2 * H_, lane, wv);
    out_mfma<4>(act, sWoT, sbout, souts, lane, wv);
    __syncthreads();   // act reads done; souts published

    // ---- dynamic MLP ----
    input_mfma(points, dirs, timev, dWinT, dbin, act, base, lane, wv);
    hidden_layer(act, dWt + 0 * 65536, dbh + 0 * H_, lane, wv);
    hidden_layer(act, dWt + 1 * 65536, dbh + 1 * H_, lane, wv);
    hidden_layer(act, dWt + 2 * 65536, dbh + 2 * H_, lane, wv);
    out_mfma<5>(act, dWoT, dbout, douts, lane, wv);
    __syncthreads();

    // ---- mix + fused render: wave 0, lane s = sample
    if (tid < 64) {
        const int s = tid;
        float so0 = souts[s * 8 + 0], so1 = souts[s * 8 + 1];
        float so2 = souts[s * 8 + 2], so3 = souts[s * 8 + 3];
        float d0 = douts[s * 8 + 0], d1 = douts[s * 8 + 1], d2 = douts[s * 8 + 2];
        float d3 = douts[s * 8 + 3], d4 = douts[s * 8 + 4];

        float bw  = sigmoidf_(d4);
        float omb = 1.f - bw;
        float sigma = omb * so0 + bw * d0;
        float cr = omb * sigmoidf_(so1) + bw * sigmoidf_(d1);
        float cg = omb * sigmoidf_(so2) + bw * sigmoidf_(d2);
        float cb = omb * sigmoidf_(so3) + bw * sigmoidf_(d3);

        float z  = z_vals[base + s];
        float zn = __shfl_down(z, 1);
        float delta = (s < 63) ? (zn - z) : FARD;
        float ex    = fminf(-sigma * delta, 60.0f);   // finite where ref overflows
        float alpha = 1.f - expf(ex);
        float f     = 1.f - alpha + 1e-10f;
        float p = f;
#pragma unroll
        for (int d = 1; d < 64; d <<= 1) {
            float pu = __shfl_up(p, d);
            if (s >= d) p *= pu;
        }
        float T = (s == 0) ? 1.f : __shfl_up(p, 1);
        float w = alpha * T;

        float* rgb_map   = out;
        float* depth_map = out + R_ * 3;
        float* weights   = out + R_ * 4;
        float* swei      = weights + N_;
        float* dwei      = swei + N_;
        weights[base + s] = w;
        swei[base + s]    = omb * w;
        dwei[base + s]    = bw * w;

        float c0 = w * cr, c1 = w * cg, c2 = w * cb, dd = w * z;
#pragma unroll
        for (int d = 32; d >= 1; d >>= 1) {
            c0 += __shfl_down(c0, d);
            c1 += __shfl_down(c1, d);
            c2 += __shfl_down(c2, d);
            dd += __shfl_down(dd, d);
        }
        if (s == 0) {
            rgb_map[ray * 3 + 0] = c0;
            rgb_map[ray * 3 + 1] = c1;
            rgb_map[ray * 3 + 2] = c2;
            depth_map[ray] = dd;
        }
    }
}

// ---- prep: all weight transposes/conversions to bf16 into ws
// layout (shorts): sWt[3*65536] dWt[3*65536] sWinT[256*32] dWinT[256*32] sWoT[16*256] dWoT[16*256]
__global__ void convert_weights(const float* __restrict__ sWh, const float* __restrict__ dWh,
                                const float* __restrict__ sWin, const float* __restrict__ dWin,
                                const float* __restrict__ sWout, const float* __restrict__ dWout,
                                short* __restrict__ ws)
{
    int idx = blockIdx.x * 256 + threadIdx.x;      // 417792 total
    float v;
    if (idx < 393216) {
        int which = idx >= 196608;
        int rem   = which ? idx - 196608 : idx;
        int l = rem >> 16, e = rem & 65535, n = e >> 8, k = e & 255;
        const float* W = which ? dWh : sWh;
        v = W[l * 65536 + k * 256 + n];
    } else if (idx < 409600) {
        int j = idx - 393216;
        int which = j >= 8192;
        int e = j & 8191;
        int n = e >> 5, k = e & 31;
        int ink = which ? 7 : 6;
        const float* W = which ? dWin : sWin;
        v = (k < ink) ? W[k * 256 + n] : 0.f;
    } else {
        int j = idx - 409600;
        int which = j >= 4096;
        int e = j & 4095;
        int o = e >> 8, k = e & 255;
        int outd = which ? 5 : 4;
        const float* W = which ? dWout : sWout;
        v = (o < outd) ? W[k * outd + o] : 0.f;
    }
    ws[idx] = (short)f2bf(v);
}

extern "C" void kernel_launch(void* const* d_in, const int* in_sizes, int n_in,
                              void* d_out, int out_size, void* d_ws, size_t ws_size,
                              hipStream_t stream)
{
    const float* points = (const float*)d_in[0];
    const float* dirs   = (const float*)d_in[1];
    const float* z_vals = (const float*)d_in[2];
    const float* timev  = (const float*)d_in[3];
    const float* sWin   = (const float*)d_in[4];
    const float* sbin   = (const float*)d_in[5];
    const float* sWh    = (const float*)d_in[6];
    const float* sbh    = (const float*)d_in[7];
    const float* sWout  = (const float*)d_in[8];
    const float* sbout  = (const float*)d_in[9];
    const float* dWin   = (const float*)d_in[10];
    const float* dbin   = (const float*)d_in[11];
    const float* dWh    = (const float*)d_in[12];
    const float* dbh    = (const float*)d_in[13];
    const float* dWout  = (const float*)d_in[14];
    const float* dbout  = (const float*)d_in[15];

    short* wsb = (short*)d_ws;

    convert_weights<<<1632, 256, 0, stream>>>(sWh, dWh, sWin, dWin, sWout, dWout, wsb);

    nerf_kernel<<<R_, 256, 0, stream>>>(
        points, dirs, z_vals, timev,
        sbin, sbh, sbout, dbin, dbh, dbout,
        wsb, (float*)d_out);
}

// Round 10
// 421.713 us; speedup vs baseline: 1.3650x; 1.3650x over previous
//
#include <hip/hip_runtime.h>

#define R_ 4096
#define S_ 64
#define H_ 256
#define N_ (R_ * S_)
#define FARD 1e10f

typedef __attribute__((ext_vector_type(4))) float f32x4;
typedef __attribute__((ext_vector_type(8))) short short8;

union U8 { short8 s; uint4 u; };

__device__ __forceinline__ unsigned int cvt_pk_bf16(float lo, float hi) {
    unsigned int r;
    asm("v_cvt_pk_bf16_f32 %0, %1, %2" : "=v"(r) : "v"(lo), "v"(hi));
    return r;
}
__device__ __forceinline__ unsigned short f2bf(float f) {
    unsigned int x = __float_as_uint(f);
    x += 0x7fffu + ((x >> 16) & 1u);          // RNE
    return (unsigned short)(x >> 16);
}
__device__ __forceinline__ float sigmoidf_(float x) { return 1.0f / (1.0f + expf(-x)); }

// Swizzled byte offset of bf16 act element (m, k); row = 512B. [T2]
__device__ __forceinline__ int act_byte(int m, int k) {
    return ((m << 9) + (k << 1)) ^ ((m & 7) << 4);
}
__device__ __forceinline__ short8 lds_read8(const unsigned short* base, int byte_off) {
    return *(const short8*)((const char*)base + byte_off);
}

// pack 4 fp32 acc -> relu -> 4 bf16 -> one 8B swizzled store
__device__ __forceinline__ void pack_store(unsigned short* act, int m, int n0, f32x4 a) {
    unsigned int u0 = cvt_pk_bf16(fmaxf(a[0], 0.f), fmaxf(a[1], 0.f));
    unsigned int u1 = cvt_pk_bf16(fmaxf(a[2], 0.f), fmaxf(a[3], 0.f));
    *(uint2*)((char*)act + act_byte(m, n0)) = make_uint2(u0, u1);
}

// ---- hidden layer, in-place, 8 waves x 32 neurons (R9 lesson: acc must be 32
// AGPR so arch(+~70) + acc fits the 128-total bin -> 4 waves/SIMD, no spill).
__device__ void hidden_layer(unsigned short* act,
                             const short* __restrict__ Wt, const float* __restrict__ bias,
                             int lane, int wv)
{
    const int m0 = lane & 15;
    const int q  = lane >> 4;
    const int nw = wv << 5;            // 32 neurons per wave

    f32x4 acc[2][4];                   // 32 AGPR
#pragma unroll
    for (int nt = 0; nt < 2; ++nt) {
        const float4 bv = *(const float4*)&bias[nw + nt * 16 + 4 * q];
#pragma unroll
        for (int mt = 0; mt < 4; ++mt) {
            acc[nt][mt][0] = bv.x; acc[nt][mt][1] = bv.y;
            acc[nt][mt][2] = bv.z; acc[nt][mt][3] = bv.w;
        }
    }

    const short* Abase = Wt + (nw + m0) * H_ + 8 * q;
#pragma unroll
    for (int kc = 0; kc < 8; ++kc) {               // K = 8 chunks of 32
        const int kb = kc * 32;
        short8 B[4];
#pragma unroll
        for (int mt = 0; mt < 4; ++mt)
            B[mt] = lds_read8(act, act_byte(mt * 16 + m0, kb + 8 * q));
#pragma unroll
        for (int nt = 0; nt < 2; ++nt) {
            short8 A = *(const short8*)(Abase + nt * 16 * H_ + kb);
#pragma unroll
            for (int mt = 0; mt < 4; ++mt)
                acc[nt][mt] = __builtin_amdgcn_mfma_f32_16x16x32_bf16(
                    A, B[mt], acc[nt][mt], 0, 0, 0);
        }
    }
    __syncthreads();   // all waves done READING act
#pragma unroll
    for (int nt = 0; nt < 2; ++nt)
#pragma unroll
        for (int mt = 0; mt < 4; ++mt)
            pack_store(act, mt * 16 + m0, nw + nt * 16 + 4 * q, acc[nt][mt]);
    __syncthreads();   // writes visible
}

// ---- input layer via MFMA (K padded to 32; only k=0..7 nonzero, held by q==0 lanes)
__device__ void input_mfma(const float* __restrict__ pts, const float* __restrict__ drs,
                           const float* __restrict__ tv,
                           const short* __restrict__ WinT, const float* __restrict__ bin,
                           unsigned short* act, int base, int lane, int wv)
{
    const int m0 = lane & 15;
    const int q  = lane >> 4;
    const int nw = wv << 5;

    short8 B[4];
#pragma unroll
    for (int mt = 0; mt < 4; ++mt) {
        U8 ub;
        if (q == 0) {
            const int s = base + mt * 16 + m0;
            float p0 = pts[s * 3 + 0], p1 = pts[s * 3 + 1], p2 = pts[s * 3 + 2];
            float e0 = drs[s * 3 + 0], e1 = drs[s * 3 + 1], e2 = drs[s * 3 + 2];
            float t  = tv[s];
            ub.u = make_uint4(cvt_pk_bf16(p0, p1), cvt_pk_bf16(p2, e0),
                              cvt_pk_bf16(e1, e2), cvt_pk_bf16(t, 0.f));
        } else {
            ub.u = make_uint4(0, 0, 0, 0);
        }
        B[mt] = ub.s;
    }

    f32x4 acc[2][4];
#pragma unroll
    for (int nt = 0; nt < 2; ++nt) {
        const float4 bv = *(const float4*)&bin[nw + nt * 16 + 4 * q];
#pragma unroll
        for (int mt = 0; mt < 4; ++mt) {
            acc[nt][mt][0] = bv.x; acc[nt][mt][1] = bv.y;
            acc[nt][mt][2] = bv.z; acc[nt][mt][3] = bv.w;
        }
    }
#pragma unroll
    for (int nt = 0; nt < 2; ++nt) {
        // rows k>=INK of WinT are zero, so q!=0 slices contribute 0
        short8 A = *(const short8*)&WinT[(nw + nt * 16 + m0) * 32 + 8 * q];
#pragma unroll
        for (int mt = 0; mt < 4; ++mt)
            acc[nt][mt] = __builtin_amdgcn_mfma_f32_16x16x32_bf16(A, B[mt], acc[nt][mt], 0, 0, 0);
    }
#pragma unroll
    for (int nt = 0; nt < 2; ++nt)
#pragma unroll
        for (int mt = 0; mt < 4; ++mt)
            pack_store(act, mt * 16 + m0, nw + nt * 16 + 4 * q, acc[nt][mt]);
    __syncthreads();
}

// ---- output layer via MFMA: waves 0-3 only; wave owns samples [16wv,16wv+16)
template <int OUTD>
__device__ void out_mfma(const unsigned short* act, const short* __restrict__ WoT,
                         const float* __restrict__ bout, float* obuf, int lane, int wv)
{
    const int m0 = lane & 15;
    const int q  = lane >> 4;
    const int m  = (wv << 4) + m0;

    f32x4 acc = {0.f, 0.f, 0.f, 0.f};
#pragma unroll
    for (int ks = 0; ks < 8; ++ks) {
        short8 A  = *(const short8*)&WoT[m0 * H_ + ks * 32 + 8 * q];
        short8 Bv = lds_read8(act, act_byte(m, ks * 32 + 8 * q));
        acc = __builtin_amdgcn_mfma_f32_16x16x32_bf16(A, Bv, acc, 0, 0, 0);
    }
    if (q == 0) {
        float4 v = make_float4(acc[0] + bout[0], acc[1] + bout[1],
                               acc[2] + bout[2], acc[3] + bout[3]);
        *(float4*)&obuf[m * 8] = v;
    }
    if (OUTD == 5 && q == 1) obuf[m * 8 + 4] = acc[0] + bout[4];
}

// 512 threads = 8 waves x 32 neurons. Total regs ~110 (32 AGPR + ~75 arch)
// -> 4 waves/SIMD = 2 blocks/CU, no spill.
__global__ __launch_bounds__(512, 4) void nerf_kernel(
    const float* __restrict__ points, const float* __restrict__ dirs,
    const float* __restrict__ z_vals, const float* __restrict__ timev,
    const float* __restrict__ sbin, const float* __restrict__ sbh, const float* __restrict__ sbout,
    const float* __restrict__ dbin, const float* __restrict__ dbh, const float* __restrict__ dbout,
    const short* __restrict__ wsb,
    float* __restrict__ out)
{
    __shared__ unsigned short act[64 * H_];     // 32KB, in-place
    __shared__ float souts[64 * 8];             // 2KB
    __shared__ float douts[64 * 8];             // 2KB

    const int tid  = threadIdx.x;
    const int lane = tid & 63;
    const int wv   = tid >> 6;
    const int ray  = blockIdx.x;
    const int base = ray * 64;

    const short* sWt   = wsb;
    const short* dWt   = wsb + 196608;
    const short* sWinT = wsb + 393216;
    const short* dWinT = wsb + 401408;
    const short* sWoT  = wsb + 409600;
    const short* dWoT  = wsb + 413696;

    // ---- static MLP ----
    input_mfma(points, dirs, timev, sWinT, sbin, act, base, lane, wv);
    hidden_layer(act, sWt + 0 * 65536, sbh + 0 * H_, lane, wv);
    hidden_layer(act, sWt + 1 * 65536, sbh + 1 * H_, lane, wv);
    hidden_layer(act, sWt + 2 * 65536, sbh + 2 * H_, lane, wv);
    if (wv < 4) out_mfma<4>(act, sWoT, sbout, souts, lane, wv);
    __syncthreads();   // act reads done; souts published

    // ---- dynamic MLP ----
    input_mfma(points, dirs, timev, dWinT, dbin, act, base, lane, wv);
    hidden_layer(act, dWt + 0 * 65536, dbh + 0 * H_, lane, wv);
    hidden_layer(act, dWt + 1 * 65536, dbh + 1 * H_, lane, wv);
    hidden_layer(act, dWt + 2 * 65536, dbh + 2 * H_, lane, wv);
    if (wv < 4) out_mfma<5>(act, dWoT, dbout, douts, lane, wv);
    __syncthreads();

    // ---- mix + fused render: wave 0, lane s = sample
    if (tid < 64) {
        const int s = tid;
        float so0 = souts[s * 8 + 0], so1 = souts[s * 8 + 1];
        float so2 = souts[s * 8 + 2], so3 = souts[s * 8 + 3];
        float d0 = douts[s * 8 + 0], d1 = douts[s * 8 + 1], d2 = douts[s * 8 + 2];
        float d3 = douts[s * 8 + 3], d4 = douts[s * 8 + 4];

        float bw  = sigmoidf_(d4);
        float omb = 1.f - bw;
        float sigma = omb * so0 + bw * d0;
        float cr = omb * sigmoidf_(so1) + bw * sigmoidf_(d1);
        float cg = omb * sigmoidf_(so2) + bw * sigmoidf_(d2);
        float cb = omb * sigmoidf_(so3) + bw * sigmoidf_(d3);

        float z  = z_vals[base + s];
        float zn = __shfl_down(z, 1);
        float delta = (s < 63) ? (zn - z) : FARD;
        float ex    = fminf(-sigma * delta, 60.0f);   // finite where ref overflows
        float alpha = 1.f - expf(ex);
        float f     = 1.f - alpha + 1e-10f;
        float p = f;
#pragma unroll
        for (int d = 1; d < 64; d <<= 1) {
            float pu = __shfl_up(p, d);
            if (s >= d) p *= pu;
        }
        float T = (s == 0) ? 1.f : __shfl_up(p, 1);
        float w = alpha * T;

        float* rgb_map   = out;
        float* depth_map = out + R_ * 3;
        float* weights   = out + R_ * 4;
        float* swei      = weights + N_;
        float* dwei      = swei + N_;
        weights[base + s] = w;
        swei[base + s]    = omb * w;
        dwei[base + s]    = bw * w;

        float c0 = w * cr, c1 = w * cg, c2 = w * cb, dd = w * z;
#pragma unroll
        for (int d = 32; d >= 1; d >>= 1) {
            c0 += __shfl_down(c0, d);
            c1 += __shfl_down(c1, d);
            c2 += __shfl_down(c2, d);
            dd += __shfl_down(dd, d);
        }
        if (s == 0) {
            rgb_map[ray * 3 + 0] = c0;
            rgb_map[ray * 3 + 1] = c1;
            rgb_map[ray * 3 + 2] = c2;
            depth_map[ray] = dd;
        }
    }
}

// ---- prep: all weight transposes/conversions to bf16 into ws
// layout (shorts): sWt[3*65536] dWt[3*65536] sWinT[256*32] dWinT[256*32] sWoT[16*256] dWoT[16*256]
__global__ void convert_weights(const float* __restrict__ sWh, const float* __restrict__ dWh,
                                const float* __restrict__ sWin, const float* __restrict__ dWin,
                                const float* __restrict__ sWout, const float* __restrict__ dWout,
                                short* __restrict__ ws)
{
    int idx = blockIdx.x * 256 + threadIdx.x;      // 417792 total
    float v;
    if (idx < 393216) {
        int which = idx >= 196608;
        int rem   = which ? idx - 196608 : idx;
        int l = rem >> 16, e = rem & 65535, n = e >> 8, k = e & 255;
        const float* W = which ? dWh : sWh;
        v = W[l * 65536 + k * 256 + n];
    } else if (idx < 409600) {
        int j = idx - 393216;
        int which = j >= 8192;
        int e = j & 8191;
        int n = e >> 5, k = e & 31;
        int ink = which ? 7 : 6;
        const float* W = which ? dWin : sWin;
        v = (k < ink) ? W[k * 256 + n] : 0.f;
    } else {
        int j = idx - 409600;
        int which = j >= 4096;
        int e = j & 4095;
        int o = e >> 8, k = e & 255;
        int outd = which ? 5 : 4;
        const float* W = which ? dWout : sWout;
        v = (o < outd) ? W[k * outd + o] : 0.f;
    }
    ws[idx] = (short)f2bf(v);
}

extern "C" void kernel_launch(void* const* d_in, const int* in_sizes, int n_in,
                              void* d_out, int out_size, void* d_ws, size_t ws_size,
                              hipStream_t stream)
{
    const float* points = (const float*)d_in[0];
    const float* dirs   = (const float*)d_in[1];
    const float* z_vals = (const float*)d_in[2];
    const float* timev  = (const float*)d_in[3];
    const float* sWin   = (const float*)d_in[4];
    const float* sbin   = (const float*)d_in[5];
    const float* sWh    = (const float*)d_in[6];
    const float* sbh    = (const float*)d_in[7];
    const float* sWout  = (const float*)d_in[8];
    const float* sbout  = (const float*)d_in[9];
    const float* dWin   = (const float*)d_in[10];
    const float* dbin   = (const float*)d_in[11];
    const float* dWh    = (const float*)d_in[12];
    const float* dbh    = (const float*)d_in[13];
    const float* dWout  = (const float*)d_in[14];
    const float* dbout  = (const float*)d_in[15];

    short* wsb = (short*)d_ws;

    convert_weights<<<1632, 256, 0, stream>>>(sWh, dWh, sWin, dWin, sWout, dWout, wsb);

    nerf_kernel<<<R_, 512, 0, stream>>>(
        points, dirs, z_vals, timev,
        sbin, sbh, sbout, dbin, dbh, dbout,
        wsb, (float*)d_out);
}